// Round 12
// baseline (949.045 us; speedup 1.0000x reference)
//
#include <hip/hip_runtime.h>
#include <hip/hip_bf16.h>

#define VOCAB 10000
#define D 200
#define NLAYERS 3
#define NB 16
#define NS 512
#define M 8192        // NB*NS
#define KA 224        // padded K for A (h3 bf16), 7 * 32
#define KB 232        // padded K for fc_w bf16; 29 16B-chunks (odd -> no LDS bank conflicts)
#define NPADA 10120   // 79*128 = 10112, +8 rows slack for unguarded staging
#define NTILES_N 79

// ws layout (bytes)
#define OFF_BUF0 0u                 // 6,553,600  embed h0, then xw1 cells
#define OFF_BUF1 6553600u           // 6,553,600  xw0 (layer-0 input proj)
#define OFF_WT   13107200u          //   480,000  w_ih transposed (all layers)
#define OFF_HBF  13587200u          // 3,670,016  h3 bf16 [M][KA]
#define OFF_FWB  17257216u          // 4,695,680  fc_w bf16 [NPADA][KB]
#define OFF_STG1 21952896u          // 6,553,600  xw2 cells
#define WS_NEED  28506496u

typedef __bf16 bf16x8 __attribute__((ext_vector_type(8)));
typedef float  f32x4  __attribute__((ext_vector_type(4)));
typedef unsigned int u32x4 __attribute__((ext_vector_type(4)));

// ---------------- embedding gather ----------------
__global__ void k_embed(const int* __restrict__ x, const float* __restrict__ emb,
                        float* __restrict__ h0) {
    int i = blockIdx.x * blockDim.x + threadIdx.x;
    if (i < M * D) {
        int bs = i / D;
        int d  = i - bs * D;
        h0[i] = emb[(size_t)x[bs] * D + d];
    }
}

// ---------------- transpose w_ih ----------------
__global__ void k_wtrans(const float* __restrict__ w_ih, float* __restrict__ wt) {
    int i = blockIdx.x * blockDim.x + threadIdx.x;
    if (i < NLAYERS * D * D) {
        int l = i / (D * D);
        int r = i - l * D * D;
        int k = r / D;
        int n = r - k * D;
        wt[i] = w_ih[l * D * D + n * D + k];
    }
}

// ---------------- fc_w -> bf16 padded ----------------
__global__ void k_fcwbf(const float* __restrict__ fc_w, __bf16* __restrict__ fwb) {
    int i = blockIdx.x * blockDim.x + threadIdx.x;
    if (i < NPADA * KB) {
        int n = i / KB;
        int k = i - n * KB;
        float v = (n < VOCAB && k < D) ? fc_w[(size_t)n * D + k] : 0.f;
        fwb[i] = (__bf16)v;
    }
}

// ---------------- h3 -> bf16 padded (fallback path only) ----------------
__global__ void k_hbf2(const float* __restrict__ h, __bf16* __restrict__ hbf) {
    int i = blockIdx.x * blockDim.x + threadIdx.x;
    if (i < M * KA) {
        int m = i / KA;
        int k = i - m * KA;
        float v = (k < D) ? h[(size_t)m * D + k] : 0.f;
        hbf[i] = (__bf16)v;
    }
}

// ---------------- zero helper ----------------
__global__ void k_zero(u32x4* __restrict__ p, int n4) {
    int i = blockIdx.x * blockDim.x + threadIdx.x;
    if (i < n4) p[i] = u32x4{0u, 0u, 0u, 0u};
}

// ---------------- xw = h @ w_ih^T + b_ih + b_hh  (f32) ----------------
__global__ void k_xw(const float* __restrict__ hin, const float* __restrict__ wt,
                     const float* __restrict__ b_ih, const float* __restrict__ b_hh,
                     float* __restrict__ xw) {
    int m0 = blockIdx.x * 32;
    int n  = threadIdx.x;
    if (n >= D) return;
    float bias = b_ih[n] + b_hh[n];
    for (int g = 0; g < 8; ++g) {
        const float* r0 = hin + (size_t)(m0 + g * 4) * D;
        float a0 = bias, a1 = bias, a2 = bias, a3 = bias;
        for (int k = 0; k < D; k += 4) {
            #pragma unroll
            for (int kk = 0; kk < 4; ++kk) {
                float w = wt[(k + kk) * D + n];
                float h0v = r0[k + kk];
                float h1v = r0[D + k + kk];
                float h2v = r0[2 * D + k + kk];
                float h3v = r0[3 * D + k + kk];
                a0 += h0v * w; a1 += h1v * w; a2 += h2v * w; a3 += h3v * w;
            }
        }
        size_t o = (size_t)(m0 + g * 4) * D + n;
        xw[o] = a0; xw[o + D] = a1; xw[o + 2 * D] = a2; xw[o + 3 * D] = a3;
    }
}

__device__ inline float fast_tanh(float x) {
    x = fminf(fmaxf(x, -15.f), 15.f);
    float e = __expf(2.f * x);
    return (e - 1.f) / (e + 1.f);
}

// ---------------- pipelined 3-layer scan, xw-handoff version ----------------
// r12 restructure of the r11 pipe (which won 1433->867): stage l now computes
// the NEXT layer's input projection itself (xw_{l+1}[s-1] = w_ih_{l+1} *
// h_l[s-1] + b), reusing the SAME 13 ds_read_b128 of h as its own wh FMAs.
// Handoff payload per row is the xw scalar; each consumer lane reads ONE cell
// for its own row (needed only at the tanh, after its FMA block) instead of
// r11's 200-cell spin -> LDS staging -> extra barrier. Stage costs: l0=208
// FMA, l1=208, l2=104; one barrier/step everywhere. Cell encoding unchanged
// (~bits(finite), 0 = unwritten, self-announcing, agent-scope relaxed).
// Exposed L3 RTT phase-locks into constant pipeline skew, not rate.
__global__ __attribute__((amdgpu_flat_work_group_size(512, 512),
                          amdgpu_waves_per_eu(2, 2)))
void k_scan_pipe(const float* __restrict__ whh_all,
                 const float* __restrict__ wih_all,   // row-major, untransposed
                 const float* __restrict__ b_ih,
                 const float* __restrict__ b_hh,
                 const float* __restrict__ xw0,       // [NB][NS][D] (bias incl.)
                 unsigned* __restrict__ cells1,       // xw for layer1 [NB][NS][200]
                 unsigned* __restrict__ cells2,       // xw for layer2
                 __bf16* __restrict__ hbf,
                 float* __restrict__ hidden) {
    __shared__ float hp0[208], hp1[208];
    const int bid = blockIdx.x;
    const int l   = bid >> 4;
    const int b   = bid & 15;
    const int t   = threadIdx.x;
    const int q   = t >> 2, dg = t & 3;
    const bool act = (q < 100);
    const int  rr  = 2 * q + (dg & 1);
    const int  rrl = act ? rr : 0;
    const bool wlane = act && (dg < 2);
    const int  dstart = dg * 52;

    f32x4 wh[2][13], wp[2][13];
    #pragma unroll
    for (int j = 0; j < 2; ++j)
        #pragma unroll
        for (int i = 0; i < 13; ++i) {
            wh[j][i] = f32x4{0.f, 0.f, 0.f, 0.f};
            wp[j][i] = f32x4{0.f, 0.f, 0.f, 0.f};
        }
    if (act) {
        #pragma unroll
        for (int j = 0; j < 2; ++j) {
            const float* wr = whh_all + (size_t)l * D * D + (size_t)(2 * q + j) * D + dstart;
            #pragma unroll
            for (int i = 0; i < 11; ++i) wh[j][i] = *(const f32x4*)(wr + 4 * i);
            if (dg < 3) {
                wh[j][11] = *(const f32x4*)(wr + 44);
                wh[j][12] = *(const f32x4*)(wr + 48);
            }
        }
        if (l < 2) {
            #pragma unroll
            for (int j = 0; j < 2; ++j) {
                const float* wr = wih_all + (size_t)(l + 1) * D * D + (size_t)(2 * q + j) * D + dstart;
                #pragma unroll
                for (int i = 0; i < 11; ++i) wp[j][i] = *(const f32x4*)(wr + 4 * i);
                if (dg < 3) {
                    wp[j][11] = *(const f32x4*)(wr + 44);
                    wp[j][12] = *(const f32x4*)(wr + 48);
                }
            }
        }
    }
    float bN = 0.f;
    if (l < 2 && act) bN = b_ih[(l + 1) * D + rr] + b_hh[(l + 1) * D + rr];

    if (t < 208) { hp0[t] = 0.f; hp1[t] = 0.f; }
    __syncthreads();

    const float* xrow = xw0 + (size_t)b * NS * D;                  // l==0 only
    const unsigned* cin = (l == 1) ? cells1 + (size_t)b * NS * 200
                        : (l == 2) ? cells2 + (size_t)b * NS * 200 : nullptr;
    unsigned* cout_ = (l == 0) ? cells1 + (size_t)b * NS * 200
                    : (l == 1) ? cells2 + (size_t)b * NS * 200 : nullptr;

    float hn_prev = 0.f;
    float xv_cur = 0.f;
    unsigned v_cur = 0u;
    if (l == 0) xv_cur = xrow[rrl];          // prefetch s=0

    #pragma unroll 1
    for (int s = 0; s <= NS; ++s) {
        float* hw = (s & 1) ? hp1 : hp0;
        if (wlane) hw[rr] = hn_prev;         // h_l[s-1]
        asm volatile("s_waitcnt lgkmcnt(0)" ::: "memory");
        __builtin_amdgcn_s_barrier();
        asm volatile("" ::: "memory");
        const float* hr = hw + dstart;

        f32x4 a0{0.f,0.f,0.f,0.f}, a1{0.f,0.f,0.f,0.f};
        f32x4 p0{0.f,0.f,0.f,0.f}, p1{0.f,0.f,0.f,0.f};
        if (l < 2) {
            #pragma unroll
            for (int i = 0; i < 13; ++i) {   // shared h reads feed wh AND wp
                f32x4 h4 = *(const f32x4*)(hr + 4 * i);
                a0 += h4 * wh[0][i];
                a1 += h4 * wh[1][i];
                p0 += h4 * wp[0][i];
                p1 += h4 * wp[1][i];
            }
        } else {
            #pragma unroll
            for (int i = 0; i < 13; ++i) {
                f32x4 h4 = *(const f32x4*)(hr + 4 * i);
                a0 += h4 * wh[0][i];
                a1 += h4 * wh[1][i];
            }
        }

        // send xw_{l+1}[s-1] (projection of h_l[s-1])
        if (l < 2 && s >= 1) {
            float t0 = (p0.x + p0.y) + (p0.z + p0.w);
            float t1 = (p1.x + p1.y) + (p1.z + p1.w);
            t0 += __shfl_xor(t0, 1);  t0 += __shfl_xor(t0, 2);
            t1 += __shfl_xor(t1, 1);  t1 += __shfl_xor(t1, 2);
            float xwp = ((dg & 1) ? t1 : t0) + bN;
            if (wlane)
                __hip_atomic_store(cout_ + (size_t)(s - 1) * 200 + rr,
                                   ~__builtin_bit_cast(unsigned, xwp),
                                   __ATOMIC_RELAXED, __HIP_MEMORY_SCOPE_AGENT);
        }

        if (s < NS) {
            float xv;
            if (l == 0) {
                xv = xv_cur;
            } else {
                unsigned v = v_cur;          // prefetched at s-1
                if (act) {
                    while (v == 0u)
                        v = __hip_atomic_load(cin + (size_t)s * 200 + rrl,
                                              __ATOMIC_RELAXED,
                                              __HIP_MEMORY_SCOPE_AGENT);
                }
                xv = __builtin_bit_cast(float, ~v);
            }
            // prefetch next step's input
            const int sp = (s + 1 < NS) ? s + 1 : NS - 1;
            if (l == 0) {
                xv_cur = xrow[(size_t)sp * D + rrl];
            } else {
                v_cur = __hip_atomic_load(cin + (size_t)sp * 200 + rrl,
                                          __ATOMIC_RELAXED,
                                          __HIP_MEMORY_SCOPE_AGENT);
            }

            float s0 = (a0.x + a0.y) + (a0.z + a0.w);
            float s1 = (a1.x + a1.y) + (a1.z + a1.w);
            s0 += __shfl_xor(s0, 1);  s0 += __shfl_xor(s0, 2);
            s1 += __shfl_xor(s1, 1);  s1 += __shfl_xor(s1, 2);
            float hn = fast_tanh(xv + ((dg & 1) ? s1 : s0));
            hn_prev = hn;
            if (l == 2 && wlane)
                hbf[((size_t)b * NS + s) * KA + rr] = (__bf16)hn;
        }
    }
    if (wlane) hidden[(size_t)l * NB * D + b * D + rr] = hn_prev;
}

// ---------------- VALU scan (r7-verified, fallback path) ----------------
#define STEP(HR, HW, SIDX)                                                  \
    {                                                                       \
        float xv = xv_next;                                                 \
        int snext = (SIDX) + 1 < NS ? (SIDX) + 1 : NS - 1;                  \
        xv_next = xrow[(size_t)snext * D + rrl];                            \
        f32x4 ac0{0.f,0.f,0.f,0.f}, ac1{0.f,0.f,0.f,0.f};                   \
        _Pragma("unroll")                                                   \
        for (int i = 0; i < 13; ++i) {                                      \
            f32x4 h4 = *(const f32x4*)((HR) + 4 * i);                       \
            ac0 += h4 * w4[0][i];                                           \
            ac1 += h4 * w4[1][i];                                           \
        }                                                                   \
        float s0 = (ac0.x + ac0.y) + (ac0.z + ac0.w);                       \
        float s1 = (ac1.x + ac1.y) + (ac1.z + ac1.w);                       \
        s0 += __shfl_xor(s0, 1);  s0 += __shfl_xor(s0, 2);                  \
        s1 += __shfl_xor(s1, 1);  s1 += __shfl_xor(s1, 2);                  \
        float hn = fast_tanh(xv + ((dg & 1) ? s1 : s0));                    \
        hlast = hn;                                                         \
        if (wlane) {                                                        \
            (HW)[rr] = hn;                                                  \
            xrow[(size_t)(SIDX) * D + rr] = hn;                             \
        }                                                                   \
        __syncthreads();                                                    \
    }

__global__ __attribute__((amdgpu_flat_work_group_size(512, 512),
                          amdgpu_waves_per_eu(2, 2)))
void k_scan(const float* __restrict__ whh,
            float* __restrict__ io,
            float* __restrict__ hidden) {
    __shared__ float hp0[208], hp1[208];
    int t  = threadIdx.x;
    int b  = blockIdx.x;
    int q  = t >> 2;
    int dg = t & 3;
    const bool act = (q < 100);
    const int  rr  = 2 * q + (dg & 1);
    const int  rrl = act ? rr : 0;
    const bool wlane = act && (dg < 2);
    const int  dstart = dg * 52;

    f32x4 w4[2][13];
    #pragma unroll
    for (int j = 0; j < 2; ++j)
        #pragma unroll
        for (int i = 0; i < 13; ++i) w4[j][i] = f32x4{0.f, 0.f, 0.f, 0.f};
    if (act) {
        #pragma unroll
        for (int j = 0; j < 2; ++j) {
            const float* wr = whh + (size_t)(2 * q + j) * D + dstart;
            #pragma unroll
            for (int i = 0; i < 11; ++i) w4[j][i] = *(const f32x4*)(wr + 4 * i);
            if (dg < 3) {
                w4[j][11] = *(const f32x4*)(wr + 44);
                w4[j][12] = *(const f32x4*)(wr + 48);
            }
        }
    }
    if (t < 208) { hp0[t] = 0.f; hp1[t] = 0.f; }
    __syncthreads();

    float* xrow = io + (size_t)b * NS * D;
    const float* hr0 = hp0 + dstart;
    const float* hr1 = hp1 + dstart;
    float xv_next = xrow[rrl];
    float hlast = 0.f;

    #pragma unroll 1
    for (int s2 = 0; s2 < NS / 2; ++s2) {
        STEP(hr0, hp1, 2 * s2)
        STEP(hr1, hp0, 2 * s2 + 1)
    }
    if (wlane) hidden[b * D + rr] = hlast;
}

// ---------------- final FC: logits = h3_bf @ fcw_bf^T + fc_b (bf16 MFMA) -----
__global__ __launch_bounds__(256) void k_fc(const __bf16* __restrict__ A,
                                            const __bf16* __restrict__ Bw,
                                            const float* __restrict__ fc_b,
                                            float* __restrict__ Cout) {
    __shared__ __bf16 Bl[3840 * 8];
    int tid = threadIdx.x;
    int wg  = blockIdx.x;
    int mt  = wg / NTILES_N, nt = wg - mt * NTILES_N;
    int m0  = mt * 128, n0 = nt * 128;

    {
        const u32x4* src = (const u32x4*)(Bw + (size_t)n0 * KB);
        u32x4* dst = (u32x4*)Bl;
        u32x4 stg[15];
        #pragma unroll
        for (int it = 0; it < 15; ++it) stg[it] = src[tid + it * 256];
        #pragma unroll
        for (int it = 0; it < 15; ++it) dst[tid + it * 256] = stg[it];
    }
    __syncthreads();

    int lane = tid & 63, wv = tid >> 6;
    int wr = wv >> 1, wc = wv & 1;
    int lr = lane & 15, lq = lane >> 4;
    f32x4 acc[4][4] = {};
    #pragma unroll
    for (int ks = 0; ks < 7; ++ks) {
        bf16x8 af[4], bfr[4];
        #pragma unroll
        for (int i = 0; i < 4; ++i) {
            int arow = m0 + wr * 64 + i * 16 + lr;
            af[i] = *(const bf16x8*)(A + (size_t)arow * KA + (ks * 4 + lq) * 8);
            int brow = wc * 64 + i * 16 + lr;
            bfr[i] = *(const bf16x8*)(Bl + brow * KB + (ks * 4 + lq) * 8);
        }
        #pragma unroll
        for (int i = 0; i < 4; ++i) {
            #pragma unroll
            for (int j = 0; j < 4; ++j) {
                acc[i][j] = __builtin_amdgcn_mfma_f32_16x16x32_bf16(af[i], bfr[j],
                                                                   acc[i][j], 0, 0, 0);
            }
        }
    }
    #pragma unroll
    for (int j = 0; j < 4; ++j) {
        int col = n0 + wc * 64 + j * 16 + lr;
        if (col < VOCAB) {
            float bias = fc_b[col];
            #pragma unroll
            for (int i = 0; i < 4; ++i) {
                #pragma unroll
                for (int r = 0; r < 4; ++r) {
                    int row = m0 + wr * 64 + i * 16 + lq * 4 + r;
                    Cout[(size_t)row * VOCAB + col] = acc[i][j][r] + bias;
                }
            }
        }
    }
}

extern "C" void kernel_launch(void* const* d_in, const int* in_sizes, int n_in,
                              void* d_out, int out_size, void* d_ws, size_t ws_size,
                              hipStream_t stream) {
    const int*   x    = (const int*)  d_in[0];
    const float* emb  = (const float*)d_in[1];
    const float* w_ih = (const float*)d_in[2];
    const float* w_hh = (const float*)d_in[3];
    const float* b_ih = (const float*)d_in[4];
    const float* b_hh = (const float*)d_in[5];
    const float* fc_w = (const float*)d_in[6];
    const float* fc_b = (const float*)d_in[7];
    float* out    = (float*)d_out;
    float* hidden = out + (size_t)M * VOCAB;

    char* ws = (char*)d_ws;
    float*    buf0 = (float*)(ws + OFF_BUF0);
    float*    buf1 = (float*)(ws + OFF_BUF1);
    float*    wt   = (float*)(ws + OFF_WT);
    __bf16*   hbf  = (__bf16*)(ws + OFF_HBF);
    __bf16*   fwb  = (__bf16*)(ws + OFF_FWB);
    unsigned* stg0 = (unsigned*)(ws + OFF_BUF0);   // xw1 cells (aliases buf0)
    unsigned* stg1 = (unsigned*)(ws + OFF_STG1);   // xw2 cells

    k_embed <<<(M * D + 255) / 256, 256, 0, stream>>>(x, emb, buf0);
    k_wtrans<<<(NLAYERS * D * D + 255) / 256, 256, 0, stream>>>(w_ih, wt);
    k_fcwbf <<<(NPADA * KB + 255) / 256, 256, 0, stream>>>(fc_w, fwb);

    if (ws_size >= WS_NEED) {
        k_xw<<<M / 32, 256, 0, stream>>>(buf0, wt, b_ih, b_hh, buf1);  // layer 0
        const int nst4 = NB * NS * 200 / 4;
        const int nhb4 = M * KA * 2 / 16;
        k_zero<<<(nst4 + 255) / 256, 256, 0, stream>>>((u32x4*)stg0, nst4);
        k_zero<<<(nst4 + 255) / 256, 256, 0, stream>>>((u32x4*)stg1, nst4);
        k_zero<<<(nhb4 + 255) / 256, 256, 0, stream>>>((u32x4*)hbf, nhb4);
        k_scan_pipe<<<NB * NLAYERS, 512, 0, stream>>>(w_hh, w_ih, b_ih, b_hh,
                                                      buf1, stg0, stg1, hbf, hidden);
    } else {
        float* cur = buf0;
        float* nxt = buf1;
        for (int l = 0; l < NLAYERS; ++l) {
            k_xw  <<<M / 32, 256, 0, stream>>>(cur, wt + l * D * D,
                                               b_ih + l * D, b_hh + l * D, nxt);
            k_scan<<<NB, 512, 0, stream>>>(w_hh + (size_t)l * D * D, nxt,
                                           hidden + l * NB * D);
            float* tswap = cur; cur = nxt; nxt = tswap;
        }
        k_hbf2<<<(M * KA + 255) / 256, 256, 0, stream>>>(cur, hbf);
    }
    k_fc<<<64 * NTILES_N, 256, 0, stream>>>(hbf, fwb, fc_b, out);
}